// Round 6
// baseline (33.218 us; speedup 1.0000x reference)
//
#include <hip/hip_runtime.h>
#include <stdint.h>

// Contrastive loss: B=16384, C=1000, D=128, fp32 in, scalar fp32 out.
// dist = f2 + c2 - 2*cross; loss = sum(relu(1-dist) over j!=target)/B.
//
// Round 6: structural collapse to 2 kernels. r3/r4/r5 (three different GEMM
// bodies) all measured 26-29us total -> cost is the surrounding structure,
// not the body. Now each block converts its OWN 128-col B slice from cls
// (L2-resident) directly into LDS fragment order + its c2 slice into LDS:
// no prep kernel, no bpre/c2p global round-trips, epilogue is LDS-only.
// Block partials + tiny reduce (r3 proved same-addr atomics serialize).
#define B_N 16384
#define C_N 1000
#define D_N 128
#define MARGIN 1.0f

typedef __attribute__((ext_vector_type(8))) short short8;  // 8 bf16
typedef __attribute__((ext_vector_type(4))) float f32x4;   // MFMA acc

__device__ __forceinline__ short f2bf(float f) {
    union { float f; uint32_t u; } v; v.f = f;
    uint32_t u = v.u;
    return (short)((u + 0x7FFFu + ((u >> 16) & 1u)) >> 16);
}

__device__ __forceinline__ short8 cvt8(const float4& v0, const float4& v1) {
    short8 s;
    s[0] = f2bf(v0.x); s[1] = f2bf(v0.y); s[2] = f2bf(v0.z); s[3] = f2bf(v0.w);
    s[4] = f2bf(v1.x); s[5] = f2bf(v1.y); s[6] = f2bf(v1.z); s[7] = f2bf(v1.w);
    return s;
}

// ---- fused kernel: block = 128 rows x 128 cols of the [16384 x 1000] tile ----
// LDS Bs fragment layout (16x16x32 MFMA B operand), per col-block nb (16 cols):
// lane (l15,kg) of fragment (nb,kk) holds cls[bx*128+nb*16+l15][kk*32+kg*8..+8]
// at shorts nb*2048 + kk*512 + lane*8.
__global__ __launch_bounds__(256, 4) void closs_kernel(
    const float* __restrict__ feat, const long long* __restrict__ tgt,
    const float* __restrict__ cls, float* __restrict__ part)
{
    __shared__ short Bs[8 * 2048];   // 32 KiB
    __shared__ float c2s[128];
    __shared__ float ws[4];

    const int tid  = threadIdx.x;
    const int wave = tid >> 6;
    const int lane = tid & 63;
    const int l15  = lane & 15;
    const int kg   = lane >> 4;
    const int bx   = blockIdx.x;                 // col slice 0..7
    const int row0 = blockIdx.y * 128 + wave * 32;

    // ---- stage + convert this block's B slice: cls -> LDS fragment order ----
    #pragma unroll
    for (int i = 0; i < 8; ++i) {
        const int idx  = tid + i * 256;          // 0..2047 lane-fragments
        const int nb   = idx >> 8;               // 0..7
        const int kk   = (idx >> 6) & 3;         // 0..3
        const int ln   = idx & 63;
        const int fl15 = ln & 15;
        const int fkg  = ln >> 4;
        const int gcol = bx * 128 + nb * 16 + fl15;
        float4 v0 = make_float4(0.f, 0.f, 0.f, 0.f), v1 = v0;
        if (gcol < C_N) {
            const float* p = cls + (size_t)gcol * D_N + kk * 32 + fkg * 8;
            v0 = *reinterpret_cast<const float4*>(p);
            v1 = *reinterpret_cast<const float4*>(p + 4);
        }
        *reinterpret_cast<short8*>(Bs + nb * 2048 + kk * 512 + ln * 8) = cvt8(v0, v1);
    }
    // ---- c2 slice (threads 0..127), straight from cls; 1e30 pad sentinel ----
    if (tid < 128) {
        const int gcol = bx * 128 + tid;
        float s = 0.f;
        if (gcol < C_N) {
            const float4* p = reinterpret_cast<const float4*>(cls + (size_t)gcol * D_N);
            #pragma unroll
            for (int q = 0; q < 32; ++q) {
                const float4 v = p[q];
                s += v.x*v.x + v.y*v.y + v.z*v.z + v.w*v.w;
            }
            c2s[tid] = s;
        } else {
            c2s[tid] = 1e30f;
        }
    }

    // ---- A prologue: 32 rows x K=128 to registers + f2 (before the barrier,
    //      overlaps the staging loads above) ----
    short8 a[2][4];
    float  t[2][4];
    int    tg[2][4];
    #pragma unroll
    for (int rg = 0; rg < 2; ++rg) {
        const float* ap = feat + (size_t)(row0 + rg * 16 + l15) * D_N + kg * 8;
        float s = 0.f;
        #pragma unroll
        for (int kk = 0; kk < 4; ++kk) {
            float4 v0 = *reinterpret_cast<const float4*>(ap + kk * 32);
            float4 v1 = *reinterpret_cast<const float4*>(ap + kk * 32 + 4);
            s += v0.x*v0.x + v0.y*v0.y + v0.z*v0.z + v0.w*v0.w
               + v1.x*v1.x + v1.y*v1.y + v1.z*v1.z + v1.w*v1.w;
            a[rg][kk] = cvt8(v0, v1);
        }
        s += __shfl_xor(s, 16);
        s += __shfl_xor(s, 32);
        #pragma unroll
        for (int r = 0; r < 4; ++r) {
            t[rg][r]  = MARGIN - __shfl(s, kg * 4 + r);
            tg[rg][r] = (int)tgt[row0 + rg * 16 + kg * 4 + r];  // int64 input
        }
    }
    __syncthreads();

    // ---- main loop: 8 col-blocks of {4 ds_read_b128, 8 MFMA, hinge} ----
    float hsum = 0.f;
    #pragma unroll
    for (int nb = 0; nb < 8; ++nb) {
        const short8* bp = reinterpret_cast<const short8*>(Bs + nb * 2048) + lane;
        short8 b0 = bp[0];
        short8 b1 = bp[64];
        short8 b2 = bp[128];
        short8 b3 = bp[192];
        f32x4 acc0 = (f32x4){0.f, 0.f, 0.f, 0.f};
        f32x4 acc1 = (f32x4){0.f, 0.f, 0.f, 0.f};
        acc0 = __builtin_amdgcn_mfma_f32_16x16x32_bf16(a[0][0], b0, acc0, 0, 0, 0);
        acc1 = __builtin_amdgcn_mfma_f32_16x16x32_bf16(a[1][0], b0, acc1, 0, 0, 0);
        acc0 = __builtin_amdgcn_mfma_f32_16x16x32_bf16(a[0][1], b1, acc0, 0, 0, 0);
        acc1 = __builtin_amdgcn_mfma_f32_16x16x32_bf16(a[1][1], b1, acc1, 0, 0, 0);
        acc0 = __builtin_amdgcn_mfma_f32_16x16x32_bf16(a[0][2], b2, acc0, 0, 0, 0);
        acc1 = __builtin_amdgcn_mfma_f32_16x16x32_bf16(a[1][2], b2, acc1, 0, 0, 0);
        acc0 = __builtin_amdgcn_mfma_f32_16x16x32_bf16(a[0][3], b3, acc0, 0, 0, 0);
        acc1 = __builtin_amdgcn_mfma_f32_16x16x32_bf16(a[1][3], b3, acc1, 0, 0, 0);

        // C/D layout (m89): col = lane&15, row = kg*4 + r.
        const int   cloc = nb * 16 + l15;
        const int   col  = bx * 128 + cloc;
        const float c2v  = c2s[cloc];     // 1e30 for padded cols -> h = 0
        #pragma unroll
        for (int r = 0; r < 4; ++r) {
            const float u0 = __builtin_fmaf(2.0f, acc0[r], t[0][r] - c2v);
            hsum += (col != tg[0][r]) ? fmaxf(0.0f, u0) : 0.0f;
            const float u1 = __builtin_fmaf(2.0f, acc1[r], t[1][r] - c2v);
            hsum += (col != tg[1][r]) ? fmaxf(0.0f, u1) : 0.0f;
        }
    }

    // ---- reduce: wave -> block -> plain store (no contended atomics) ----
    #pragma unroll
    for (int off = 32; off; off >>= 1) hsum += __shfl_down(hsum, off);
    if (lane == 0) ws[wave] = hsum;
    __syncthreads();
    if (tid == 0)
        part[blockIdx.y * gridDim.x + blockIdx.x] = ws[0] + ws[1] + ws[2] + ws[3];
}

// ---- reduce 1024 partials -> out[0] ----
__global__ __launch_bounds__(256) void reduce_kernel(
    const float* __restrict__ part, float* __restrict__ out)
{
    const int tid = threadIdx.x;
    float s = part[tid] + part[tid + 256] + part[tid + 512] + part[tid + 768];
    #pragma unroll
    for (int off = 32; off; off >>= 1) s += __shfl_down(s, off);
    __shared__ float ws[4];
    if ((tid & 63) == 0) ws[tid >> 6] = s;
    __syncthreads();
    if (tid == 0) out[0] = (ws[0] + ws[1] + ws[2] + ws[3]) * (1.0f / 16384.0f);
}

extern "C" void kernel_launch(void* const* d_in, const int* in_sizes, int n_in,
                              void* d_out, int out_size, void* d_ws, size_t ws_size,
                              hipStream_t stream) {
    const float*     feat = (const float*)d_in[0];
    const long long* tgt  = (const long long*)d_in[1];   // int64 targets
    const float*     cls  = (const float*)d_in[2];
    float*           out  = (float*)d_out;

    float* part = (float*)d_ws;                          // 4 KiB partials

    closs_kernel<<<dim3(8, 128), 256, 0, stream>>>(feat, tgt, cls, part);
    reduce_kernel<<<1, 256, 0, stream>>>(part, out);
}